// Round 11
// baseline (130.846 us; speedup 1.0000x reference)
//
#include <hip/hip_runtime.h>
#include <hip/hip_bf16.h>

#define BATCH   2048
#define NFIELDS 32
#define EMBED   64
#define NPAIRS  496

typedef __attribute__((ext_vector_type(8))) short bf16x8;
typedef __attribute__((ext_vector_type(4))) float f32x4;

__device__ __forceinline__ unsigned short f2bf(float x) {
    unsigned int u = __float_as_uint(x);
    unsigned int r = 0x7fffu + ((u >> 16) & 1u);
    return (unsigned short)((u + r) >> 16);
}
__device__ __forceinline__ float bf2f(unsigned short b) {
    return __uint_as_float(((unsigned int)b) << 16);
}
__device__ __forceinline__ bf16x8 cvt8(const float* p) {
    float4 v0 = *(const float4*)p;
    float4 v1 = *(const float4*)(p + 4);
    bf16x8 o;
    o[0]=(short)f2bf(v0.x); o[1]=(short)f2bf(v0.y); o[2]=(short)f2bf(v0.z); o[3]=(short)f2bf(v0.w);
    o[4]=(short)f2bf(v1.x); o[5]=(short)f2bf(v1.y); o[6]=(short)f2bf(v1.z); o[7]=(short)f2bf(v1.w);
    return o;
}

// Prepass: emb fp32 -> bf16 (same layout); kernel fp32 [i][p][j] -> bf16 [p][i][j]
__global__ __launch_bounds__(256) void convert_prepass(
    const float* __restrict__ emb, const float* __restrict__ kern,
    unsigned short* __restrict__ embB, unsigned short* __restrict__ kernB)
{
    const int EMB4 = BATCH * NFIELDS * EMBED / 4;   // 1048576
    const int KER4 = EMBED * NPAIRS * EMBED / 4;    // 507904
    int t = blockIdx.x * blockDim.x + threadIdx.x;
    if (t < EMB4) {
        float4 v = ((const float4*)emb)[t];
        ushort4 o;
        o.x = f2bf(v.x); o.y = f2bf(v.y); o.z = f2bf(v.z); o.w = f2bf(v.w);
        *(ushort4*)(embB + (size_t)t * 4) = o;
    } else if (t < EMB4 + KER4) {
        int u = t - EMB4;
        int j4   = u & 15;
        int rest = u >> 4;
        int p = rest % NPAIRS;
        int i = rest / NPAIRS;
        float4 v = *(const float4*)(kern + (size_t)i * (NPAIRS*EMBED) + (size_t)p * EMBED + j4*4);
        ushort4 o;
        o.x = f2bf(v.x); o.y = f2bf(v.y); o.z = f2bf(v.z); o.w = f2bf(v.w);
        *(ushort4*)(kernB + (size_t)p * 4096 + i * 64 + j4 * 4) = o;
    }
}

// Main: block = (4-pair chunk, 64-batch tile). 4 waves; wave w owns pair chunk*4+w.
// D[m=i][n=batch] = sum_j K_p[i,j]*emb[b,r,j]; A=K rows in regs, B=emb_r, q bf16.
// MLP fix: ALL 4 iterations' B-fragments + q-vectors preloaded into distinct regs
// (24 loads in flight per wave), sched_barrier fence, then compute.
// XCD swizzle: x=bid&7 pins XCD; bt=(hi&3)*8+x -> each XCD owns 256 batches
// (1 MB bf16 emb slice, L2-resident all kernel); chunk=hi>>2 -> K streams 32KB/chunk.
template<bool PRE>
__global__ __launch_bounds__(256) void opn_fused(
    const void* __restrict__ embP, const void* __restrict__ kernP,
    const float* __restrict__ embF, float* __restrict__ out)
{
    const int bid = blockIdx.x;
    const int x  = bid & 7;
    const int hi = bid >> 3;               // 0..495
    const int chunk = hi >> 2;             // 0..123
    const int bt    = ((hi & 3) << 3) | x; // 0..31

    const int tid  = threadIdx.x;
    const int wave = tid >> 6, lane = tid & 63;
    const int col  = lane & 15, quad = lane >> 4;
    const int pair = chunk * 4 + wave;

    // decode pair -> (r, c), triu k=1 row-major
    int r = 0, s = 0;
    while (pair >= s + (NFIELDS - 1 - r)) { s += NFIELDS - 1 - r; ++r; }
    const int c = r + 1 + (pair - s);

    __shared__ __align__(16) float Otile[64][4];

    // ---- A fragments: lane holds K_p[i = nt*16+col][j = ks*32 + quad*8 + t] ----
    bf16x8 kfr[4][2];
    if (PRE) {
        const unsigned short* kb = (const unsigned short*)kernP + (size_t)pair * 4096;
        #pragma unroll
        for (int nt = 0; nt < 4; ++nt)
            #pragma unroll
            for (int ks = 0; ks < 2; ++ks)
                kfr[nt][ks] = *(const bf16x8*)(kb + (nt*16 + col) * 64 + ks*32 + quad*8);
    } else {
        const float* kf = (const float*)kernP;
        #pragma unroll
        for (int nt = 0; nt < 4; ++nt)
            #pragma unroll
            for (int ks = 0; ks < 2; ++ks)
                kfr[nt][ks] = cvt8(kf + (size_t)(nt*16 + col) * (NPAIRS*EMBED)
                                     + (size_t)pair * EMBED + ks*32 + quad*8);
    }

    // ---- preload ALL 4 iterations (forces loads in flight) ----
    bf16x8 bfr[4][2];
    ushort4 qv[4][4];
    #pragma unroll
    for (int it = 0; it < 4; ++it) {
        const int brow = bt * 64 + it * 16 + col;
        if (PRE) {
            const unsigned short* eb = (const unsigned short*)embP
                                     + ((size_t)brow * NFIELDS + r) * EMBED;
            bfr[it][0] = *(const bf16x8*)(eb + quad*8);
            bfr[it][1] = *(const bf16x8*)(eb + 32 + quad*8);
            const unsigned short* qb = (const unsigned short*)embP
                                     + ((size_t)brow * NFIELDS + c) * EMBED + quad*4;
            #pragma unroll
            for (int nt = 0; nt < 4; ++nt)
                qv[it][nt] = *(const ushort4*)(qb + nt*16);
        } else {
            const float* ef = (const float*)embP + ((size_t)brow * NFIELDS + r) * EMBED;
            bfr[it][0] = cvt8(ef + quad*8);
            bfr[it][1] = cvt8(ef + 32 + quad*8);
            const float* qp = embF + ((size_t)brow * NFIELDS + c) * EMBED + quad*4;
            #pragma unroll
            for (int nt = 0; nt < 4; ++nt) {
                f32x4 q = *(const f32x4*)(qp + nt*16);
                qv[it][nt].x = f2bf(q[0]); qv[it][nt].y = f2bf(q[1]);
                qv[it][nt].z = f2bf(q[2]); qv[it][nt].w = f2bf(q[3]);
            }
        }
    }
    __builtin_amdgcn_sched_barrier(0);   // loads stay above; compute waits below

    #pragma unroll
    for (int it = 0; it < 4; ++it) {
        float partial = 0.f;
        #pragma unroll
        for (int nt = 0; nt < 4; ++nt) {
            f32x4 acc = {0.f, 0.f, 0.f, 0.f};
            acc = __builtin_amdgcn_mfma_f32_16x16x32_bf16(kfr[nt][0], bfr[it][0], acc, 0, 0, 0);
            acc = __builtin_amdgcn_mfma_f32_16x16x32_bf16(kfr[nt][1], bfr[it][1], acc, 0, 0, 0);
            partial += acc[0]*bf2f(qv[it][nt].x) + acc[1]*bf2f(qv[it][nt].y)
                     + acc[2]*bf2f(qv[it][nt].z) + acc[3]*bf2f(qv[it][nt].w);
        }
        // reduce over i: lanes {col, col+16, col+32, col+48}
        partial += __shfl_xor(partial, 16, 64);
        partial += __shfl_xor(partial, 32, 64);
        if (quad == 0) Otile[it*16 + col][wave] = partial;
    }
    __syncthreads();

    if (tid < 64) {
        f32x4 o = *(const f32x4*)&Otile[tid][0];
        *(f32x4*)&out[((size_t)(bt*64 + tid)) * NPAIRS + chunk*4] = o;
    }
}

extern "C" void kernel_launch(void* const* d_in, const int* in_sizes, int n_in,
                              void* d_out, int out_size, void* d_ws, size_t ws_size,
                              hipStream_t stream) {
    const float* emb  = (const float*)d_in[0];   // (2048, 32, 64) fp32
    const float* kern = (const float*)d_in[1];   // (64, 496, 64) fp32
    float* out = (float*)d_out;                  // (2048, 1, 496) fp32

    const size_t embElems  = (size_t)BATCH * NFIELDS * EMBED;   // 4194304
    const size_t kernElems = (size_t)EMBED * NPAIRS * EMBED;    // 2031616
    const size_t need = (embElems + kernElems) * sizeof(unsigned short);

    if (ws_size >= need) {
        unsigned short* embB  = (unsigned short*)d_ws;
        unsigned short* kernB = embB + embElems;
        int total4 = (int)((embElems + kernElems) / 4);         // 1556480
        convert_prepass<<<(total4 + 255) / 256, 256, 0, stream>>>(emb, kern, embB, kernB);
        opn_fused<true><<<dim3(3968), 256, 0, stream>>>(
            (const void*)embB, (const void*)kernB, emb, out);
    } else {
        opn_fused<false><<<dim3(3968), 256, 0, stream>>>(
            (const void*)emb, (const void*)kern, emb, out);
    }
}

// Round 12
// 120.672 us; speedup vs baseline: 1.0843x; 1.0843x over previous
//
#include <hip/hip_runtime.h>
#include <hip/hip_bf16.h>
#include <math.h>

#define BATCH   2048
#define NFIELDS 32
#define EMBED   64
#define NPAIRS  496

typedef __attribute__((ext_vector_type(8))) short bf16x8;
typedef __attribute__((ext_vector_type(4))) float f32x4;

__device__ __forceinline__ unsigned short f2bf(float x) {
    unsigned int u = __float_as_uint(x);
    unsigned int r = 0x7fffu + ((u >> 16) & 1u);
    return (unsigned short)((u + r) >> 16);
}
__device__ __forceinline__ float bf2f(unsigned short b) {
    return __uint_as_float(((unsigned int)b) << 16);
}
__device__ __forceinline__ bf16x8 cvt8(const float* p) {
    float4 v0 = *(const float4*)p;
    float4 v1 = *(const float4*)(p + 4);
    bf16x8 o;
    o[0]=(short)f2bf(v0.x); o[1]=(short)f2bf(v0.y); o[2]=(short)f2bf(v0.z); o[3]=(short)f2bf(v0.w);
    o[4]=(short)f2bf(v1.x); o[5]=(short)f2bf(v1.y); o[6]=(short)f2bf(v1.z); o[7]=(short)f2bf(v1.w);
    return o;
}

// Prepass: emb fp32 -> bf16 (same layout); kernel fp32 [i][p][j] -> bf16 [p][i][j]
__global__ __launch_bounds__(256) void convert_prepass(
    const float* __restrict__ emb, const float* __restrict__ kern,
    unsigned short* __restrict__ embB, unsigned short* __restrict__ kernB)
{
    const int EMB4 = BATCH * NFIELDS * EMBED / 4;   // 1048576
    const int KER4 = EMBED * NPAIRS * EMBED / 4;    // 507904
    int t = blockIdx.x * blockDim.x + threadIdx.x;
    if (t < EMB4) {
        float4 v = ((const float4*)emb)[t];
        ushort4 o;
        o.x = f2bf(v.x); o.y = f2bf(v.y); o.z = f2bf(v.z); o.w = f2bf(v.w);
        *(ushort4*)(embB + (size_t)t * 4) = o;
    } else if (t < EMB4 + KER4) {
        int u = t - EMB4;
        int j4   = u & 15;
        int rest = u >> 4;
        int p = rest % NPAIRS;
        int i = rest / NPAIRS;
        float4 v = *(const float4*)(kern + (size_t)i * (NPAIRS*EMBED) + (size_t)p * EMBED + j4*4);
        ushort4 o;
        o.x = f2bf(v.x); o.y = f2bf(v.y); o.z = f2bf(v.z); o.w = f2bf(v.w);
        *(ushort4*)(kernB + (size_t)p * 4096 + i * 64 + j4 * 4) = o;
    }
}

// Main: 992 blocks = 124 chunks x 8 batch-tiles(256). ALL blocks co-resident in one
// generation (3.9 blocks/CU). Wave w owns pair chunk*4+w for 256 batches (16 its).
// Fixed per-wave costs (decode, K-frag loads) paid 4x less often than R11.
// Closed-form triu decode (sqrt + fixup) replaces the 31-iter divergent loop.
// bt = bid&7 pins each 256-batch emb slice (1 MB bf16) to one XCD's L2 under
// round-robin block->XCD dispatch; K walks chunks synchronously (L3 serves 7/8).
template<bool PRE>
__global__ __launch_bounds__(256, 4) void opn_fused(
    const void* __restrict__ embP, const void* __restrict__ kernP,
    const float* __restrict__ embF, float* __restrict__ out)
{
    const int bid   = blockIdx.x;
    const int chunk = bid >> 3;            // 0..123
    const int bt    = bid & 7;             // 0..7 == XCD id (round-robin dispatch)

    const int tid  = threadIdx.x;
    const int wave = tid >> 6, lane = tid & 63;
    const int col  = lane & 15, quad = lane >> 4;
    const int pair = chunk * 4 + wave;

    // closed-form triu k=1 decode: S(r) = r*(63-r)/2 pairs precede row r
    int r;
    {
        float sq = sqrtf((float)(3969 - 8 * pair));   // 3969 = 63^2
        r = (int)((63.0f - sq) * 0.5f);
        if (r > 0 && r * (63 - r) / 2 > pair) --r;
        if ((r + 1) * (63 - (r + 1)) / 2 <= pair) ++r;
    }
    const int c = r + 1 + (pair - r * (63 - r) / 2);

    __shared__ __align__(16) float Otile[256][4];

    // ---- A fragments: lane holds K_p[i = nt*16+col][j = ks*32 + quad*8 + t] ----
    bf16x8 kfr[4][2];
    if (PRE) {
        const unsigned short* kb = (const unsigned short*)kernP + (size_t)pair * 4096;
        #pragma unroll
        for (int nt = 0; nt < 4; ++nt)
            #pragma unroll
            for (int ks = 0; ks < 2; ++ks)
                kfr[nt][ks] = *(const bf16x8*)(kb + (nt*16 + col) * 64 + ks*32 + quad*8);
    } else {
        const float* kf = (const float*)kernP;
        #pragma unroll
        for (int nt = 0; nt < 4; ++nt)
            #pragma unroll
            for (int ks = 0; ks < 2; ++ks)
                kfr[nt][ks] = cvt8(kf + (size_t)(nt*16 + col) * (NPAIRS*EMBED)
                                     + (size_t)pair * EMBED + ks*32 + quad*8);
    }

    float res[16];

    #pragma unroll
    for (int it = 0; it < 16; ++it) {
        const int brow = bt * 256 + it * 16 + col;

        bf16x8 bfr0, bfr1;
        ushort4 qv[4];
        if (PRE) {
            const unsigned short* eb = (const unsigned short*)embP
                                     + ((size_t)brow * NFIELDS + r) * EMBED;
            bfr0 = *(const bf16x8*)(eb + quad*8);
            bfr1 = *(const bf16x8*)(eb + 32 + quad*8);
            const unsigned short* qb = (const unsigned short*)embP
                                     + ((size_t)brow * NFIELDS + c) * EMBED + quad*4;
            #pragma unroll
            for (int nt = 0; nt < 4; ++nt)
                qv[nt] = *(const ushort4*)(qb + nt*16);
        } else {
            const float* ef = (const float*)embP + ((size_t)brow * NFIELDS + r) * EMBED;
            bfr0 = cvt8(ef + quad*8);
            bfr1 = cvt8(ef + 32 + quad*8);
            const float* qp = embF + ((size_t)brow * NFIELDS + c) * EMBED + quad*4;
            #pragma unroll
            for (int nt = 0; nt < 4; ++nt) {
                f32x4 q = *(const f32x4*)(qp + nt*16);
                qv[nt].x = f2bf(q[0]); qv[nt].y = f2bf(q[1]);
                qv[nt].z = f2bf(q[2]); qv[nt].w = f2bf(q[3]);
            }
        }

        float partial = 0.f;
        #pragma unroll
        for (int nt = 0; nt < 4; ++nt) {
            f32x4 acc = {0.f, 0.f, 0.f, 0.f};
            acc = __builtin_amdgcn_mfma_f32_16x16x32_bf16(kfr[nt][0], bfr0, acc, 0, 0, 0);
            acc = __builtin_amdgcn_mfma_f32_16x16x32_bf16(kfr[nt][1], bfr1, acc, 0, 0, 0);
            partial += acc[0]*bf2f(qv[nt].x) + acc[1]*bf2f(qv[nt].y)
                     + acc[2]*bf2f(qv[nt].z) + acc[3]*bf2f(qv[nt].w);
        }
        // reduce over i: lanes {col, col+16, col+32, col+48}
        partial += __shfl_xor(partial, 16, 64);
        partial += __shfl_xor(partial, 32, 64);
        res[it] = partial;
    }

    if (quad == 0) {
        #pragma unroll
        for (int it = 0; it < 16; ++it)
            Otile[it*16 + col][wave] = res[it];
    }
    __syncthreads();

    {
        f32x4 o = *(const f32x4*)&Otile[tid][0];
        *(f32x4*)&out[((size_t)(bt*256 + tid)) * NPAIRS + chunk*4] = o;
    }
}

extern "C" void kernel_launch(void* const* d_in, const int* in_sizes, int n_in,
                              void* d_out, int out_size, void* d_ws, size_t ws_size,
                              hipStream_t stream) {
    const float* emb  = (const float*)d_in[0];   // (2048, 32, 64) fp32
    const float* kern = (const float*)d_in[1];   // (64, 496, 64) fp32
    float* out = (float*)d_out;                  // (2048, 1, 496) fp32

    const size_t embElems  = (size_t)BATCH * NFIELDS * EMBED;   // 4194304
    const size_t kernElems = (size_t)EMBED * NPAIRS * EMBED;    // 2031616
    const size_t need = (embElems + kernElems) * sizeof(unsigned short);

    if (ws_size >= need) {
        unsigned short* embB  = (unsigned short*)d_ws;
        unsigned short* kernB = embB + embElems;
        int total4 = (int)((embElems + kernElems) / 4);         // 1556480
        convert_prepass<<<(total4 + 255) / 256, 256, 0, stream>>>(emb, kern, embB, kernB);
        opn_fused<true><<<dim3(992), 256, 0, stream>>>(
            (const void*)embB, (const void*)kernB, emb, out);
    } else {
        opn_fused<false><<<dim3(992), 256, 0, stream>>>(
            (const void*)emb, (const void*)kern, emb, out);
    }
}

// Round 18
// 107.920 us; speedup vs baseline: 1.2124x; 1.1182x over previous
//
#include <hip/hip_runtime.h>
#include <hip/hip_bf16.h>
#include <math.h>

#define BATCH   2048
#define NFIELDS 32
#define EMBED   64
#define NPAIRS  496

typedef __attribute__((ext_vector_type(8))) short bf16x8;
typedef __attribute__((ext_vector_type(4))) float f32x4;

__device__ __forceinline__ unsigned short f2bf(float x) {
    unsigned int u = __float_as_uint(x);
    unsigned int r = 0x7fffu + ((u >> 16) & 1u);
    return (unsigned short)((u + r) >> 16);
}
__device__ __forceinline__ float bf2f(unsigned short b) {
    return __uint_as_float(((unsigned int)b) << 16);
}
__device__ __forceinline__ bf16x8 cvt8(const float* p) {
    float4 v0 = *(const float4*)p;
    float4 v1 = *(const float4*)(p + 4);
    bf16x8 o;
    o[0]=(short)f2bf(v0.x); o[1]=(short)f2bf(v0.y); o[2]=(short)f2bf(v0.z); o[3]=(short)f2bf(v0.w);
    o[4]=(short)f2bf(v1.x); o[5]=(short)f2bf(v1.y); o[6]=(short)f2bf(v1.z); o[7]=(short)f2bf(v1.w);
    return o;
}

// Prepass: emb fp32 -> bf16 (same layout); kernel fp32 [i][p][j] -> bf16 [p][i][j]
__global__ __launch_bounds__(256) void convert_prepass(
    const float* __restrict__ emb, const float* __restrict__ kern,
    unsigned short* __restrict__ embB, unsigned short* __restrict__ kernB)
{
    const int EMB4 = BATCH * NFIELDS * EMBED / 4;   // 1048576
    const int KER4 = EMBED * NPAIRS * EMBED / 4;    // 507904
    int t = blockIdx.x * blockDim.x + threadIdx.x;
    if (t < EMB4) {
        float4 v = ((const float4*)emb)[t];
        ushort4 o;
        o.x = f2bf(v.x); o.y = f2bf(v.y); o.z = f2bf(v.z); o.w = f2bf(v.w);
        *(ushort4*)(embB + (size_t)t * 4) = o;
    } else if (t < EMB4 + KER4) {
        int u = t - EMB4;
        int j4   = u & 15;
        int rest = u >> 4;
        int p = rest % NPAIRS;
        int i = rest / NPAIRS;
        float4 v = *(const float4*)(kern + (size_t)i * (NPAIRS*EMBED) + (size_t)p * EMBED + j4*4);
        ushort4 o;
        o.x = f2bf(v.x); o.y = f2bf(v.y); o.z = f2bf(v.z); o.w = f2bf(v.w);
        *(ushort4*)(kernB + (size_t)p * 4096 + i * 64 + j4 * 4) = o;
    }
}

// Main: 992 blocks = 124 chunks x 8 batch-tiles(256). Wave w owns pair chunk*4+w,
// 16 iterations of 16 batches. Per-wave LDS double-buffer filled by
// global_load_lds DMA; counted s_waitcnt vmcnt(4) keeps the next iteration's
// 4 loads in flight during compute. No block barriers in the loop.
// SEG-MAJOR LDS layout (correct-by-construction, no XOR):
//   LDSbyte(row, seg) = seg*256 + row*16   (row=batch row 0..15, seg=j/8, 16B slots)
// DMA lane l sources (row = l&15, seg = l>>4): l*16 == (l>>4)*256 + (l&15)*16,
// so write side and read side instantiate the SAME layout equation.
// Bank cost: B-frag b128 8-way (~2.9x), q b64 4-way (~1.6x) - throughput, acceptable.
template<bool PRE>
__global__ __launch_bounds__(256, 4) void opn_fused(
    const void* __restrict__ embP, const void* __restrict__ kernP,
    const float* __restrict__ embF, float* __restrict__ out)
{
    const int bid   = blockIdx.x;
    const int chunk = bid >> 3;            // 0..123
    const int bt    = bid & 7;             // 0..7 == XCD id (round-robin dispatch)

    const int tid  = threadIdx.x;
    const int wave = tid >> 6, lane = tid & 63;
    const int col  = lane & 15, quad = lane >> 4;
    const int pair = chunk * 4 + wave;

    // closed-form triu k=1 decode (R12-proven)
    int r;
    {
        float sq = sqrtf((float)(3969 - 8 * pair));   // 3969 = 63^2
        r = (int)((63.0f - sq) * 0.5f);
        if (r > 0 && r * (63 - r) / 2 > pair) --r;
        if ((r + 1) * (63 - (r + 1)) / 2 <= pair) ++r;
    }
    const int c = r + 1 + (pair - r * (63 - r) / 2);

    __shared__ __align__(16) unsigned short Stage[4][2][2][1024]; // [wave][buf][r/c][2KB]
    __shared__ __align__(16) float Otile[256][4];

    // ---- A fragments: lane holds K_p[i = nt*16+col][j = ks*32 + quad*8 + t] ----
    bf16x8 kfr[4][2];
    if (PRE) {
        const unsigned short* kb = (const unsigned short*)kernP + (size_t)pair * 4096;
        #pragma unroll
        for (int nt = 0; nt < 4; ++nt)
            #pragma unroll
            for (int ks = 0; ks < 2; ++ks)
                kfr[nt][ks] = *(const bf16x8*)(kb + (nt*16 + col) * 64 + ks*32 + quad*8);
    } else {
        const float* kf = (const float*)kernP;
        #pragma unroll
        for (int nt = 0; nt < 4; ++nt)
            #pragma unroll
            for (int ks = 0; ks < 2; ++ks)
                kfr[nt][ks] = cvt8(kf + (size_t)(nt*16 + col) * (NPAIRS*EMBED)
                                     + (size_t)pair * EMBED + ks*32 + quad*8);
    }

    float res[16];

    if (PRE) {
        const unsigned short* eb = (const unsigned short*)embP;
        // per-lane DMA source: batch row rr = lane&15, seg ss = lane>>4 (segs 0..3;
        // second DMA covers segs 4..7 via +32 ushorts)
        const int rr = lane & 15;
        const int ss = lane >> 4;
        const int brow0 = bt * 256;
        const unsigned short* gr = eb + ((size_t)(brow0 + rr) * NFIELDS + r) * EMBED + ss*8;
        const unsigned short* gc = eb + ((size_t)(brow0 + rr) * NFIELDS + c) * EMBED + ss*8;
        const size_t itstride = (size_t)16 * NFIELDS * EMBED;   // 16 batch rows

        // read offsets (bytes) in the seg-major layout
        const unsigned offB0 = (unsigned)quad * 256 + (unsigned)col * 16;        // seg=quad
        const unsigned offB1 = offB0 + 1024;                                     // seg=4+quad
        unsigned offQ[4];
        #pragma unroll
        for (int nt = 0; nt < 4; ++nt)
            offQ[nt] = (unsigned)(2*nt + (quad >> 1)) * 256
                     + (unsigned)col * 16 + (unsigned)(quad & 1) * 8;

        #define STAGE(itv, bufv) do {                                                     \
            const unsigned short* _r = gr + (size_t)(itv) * itstride;                     \
            const unsigned short* _c = gc + (size_t)(itv) * itstride;                     \
            __builtin_amdgcn_global_load_lds(                                             \
                (const __attribute__((address_space(1))) void*)_r,                        \
                (__attribute__((address_space(3))) void*)&Stage[wave][bufv][0][0],   16, 0, 0); \
            __builtin_amdgcn_global_load_lds(                                             \
                (const __attribute__((address_space(1))) void*)(_r + 32),                 \
                (__attribute__((address_space(3))) void*)&Stage[wave][bufv][0][512], 16, 0, 0); \
            __builtin_amdgcn_global_load_lds(                                             \
                (const __attribute__((address_space(1))) void*)_c,                        \
                (__attribute__((address_space(3))) void*)&Stage[wave][bufv][1][0],   16, 0, 0); \
            __builtin_amdgcn_global_load_lds(                                             \
                (const __attribute__((address_space(1))) void*)(_c + 32),                 \
                (__attribute__((address_space(3))) void*)&Stage[wave][bufv][1][512], 16, 0, 0); \
        } while (0)

        STAGE(0, 0);

        #pragma unroll
        for (int it = 0; it < 16; ++it) {
            const int buf = it & 1;
            if (it < 15) {
                STAGE(it + 1, buf ^ 1);
                asm volatile("s_waitcnt vmcnt(4)" ::: "memory");  // current buf's 4 done
            } else {
                asm volatile("s_waitcnt vmcnt(0)" ::: "memory");
            }
            __builtin_amdgcn_sched_barrier(0);

            const char* rb = (const char*)&Stage[wave][buf][0][0];
            const char* cb = (const char*)&Stage[wave][buf][1][0];
            bf16x8 bfr0 = *(const bf16x8*)(rb + offB0);
            bf16x8 bfr1 = *(const bf16x8*)(rb + offB1);
            ushort4 qv[4];
            #pragma unroll
            for (int nt = 0; nt < 4; ++nt)
                qv[nt] = *(const ushort4*)(cb + offQ[nt]);

            float partial = 0.f;
            #pragma unroll
            for (int nt = 0; nt < 4; ++nt) {
                f32x4 acc = {0.f, 0.f, 0.f, 0.f};
                acc = __builtin_amdgcn_mfma_f32_16x16x32_bf16(kfr[nt][0], bfr0, acc, 0, 0, 0);
                acc = __builtin_amdgcn_mfma_f32_16x16x32_bf16(kfr[nt][1], bfr1, acc, 0, 0, 0);
                partial += acc[0]*bf2f(qv[nt].x) + acc[1]*bf2f(qv[nt].y)
                         + acc[2]*bf2f(qv[nt].z) + acc[3]*bf2f(qv[nt].w);
            }
            partial += __shfl_xor(partial, 16, 64);
            partial += __shfl_xor(partial, 32, 64);
            res[it] = partial;
        }
        #undef STAGE
    } else {
        // fallback: direct fp32 path (R12)
        #pragma unroll
        for (int it = 0; it < 16; ++it) {
            const int brow = bt * 256 + it * 16 + col;
            const float* ef = (const float*)embP + ((size_t)brow * NFIELDS + r) * EMBED;
            bf16x8 bfr0 = cvt8(ef + quad*8);
            bf16x8 bfr1 = cvt8(ef + 32 + quad*8);
            const float* qp = embF + ((size_t)brow * NFIELDS + c) * EMBED + quad*4;
            float partial = 0.f;
            #pragma unroll
            for (int nt = 0; nt < 4; ++nt) {
                f32x4 q = *(const f32x4*)(qp + nt*16);
                f32x4 acc = {0.f, 0.f, 0.f, 0.f};
                acc = __builtin_amdgcn_mfma_f32_16x16x32_bf16(kfr[nt][0], bfr0, acc, 0, 0, 0);
                acc = __builtin_amdgcn_mfma_f32_16x16x32_bf16(kfr[nt][1], bfr1, acc, 0, 0, 0);
                partial += acc[0]*q[0] + acc[1]*q[1] + acc[2]*q[2] + acc[3]*q[3];
            }
            partial += __shfl_xor(partial, 16, 64);
            partial += __shfl_xor(partial, 32, 64);
            res[it] = partial;
        }
    }

    if (quad == 0) {
        #pragma unroll
        for (int it = 0; it < 16; ++it)
            Otile[it*16 + col][wave] = res[it];
    }
    __syncthreads();

    {
        f32x4 o = *(const f32x4*)&Otile[tid][0];
        *(f32x4*)&out[((size_t)(bt*256 + tid)) * NPAIRS + chunk*4] = o;
    }
}

extern "C" void kernel_launch(void* const* d_in, const int* in_sizes, int n_in,
                              void* d_out, int out_size, void* d_ws, size_t ws_size,
                              hipStream_t stream) {
    const float* emb  = (const float*)d_in[0];   // (2048, 32, 64) fp32
    const float* kern = (const float*)d_in[1];   // (64, 496, 64) fp32
    float* out = (float*)d_out;                  // (2048, 1, 496) fp32

    const size_t embElems  = (size_t)BATCH * NFIELDS * EMBED;   // 4194304
    const size_t kernElems = (size_t)EMBED * NPAIRS * EMBED;    // 2031616
    const size_t need = (embElems + kernElems) * sizeof(unsigned short);

    if (ws_size >= need) {
        unsigned short* embB  = (unsigned short*)d_ws;
        unsigned short* kernB = embB + embElems;
        int total4 = (int)((embElems + kernElems) / 4);         // 1556480
        convert_prepass<<<(total4 + 255) / 256, 256, 0, stream>>>(emb, kern, embB, kernB);
        opn_fused<true><<<dim3(992), 256, 0, stream>>>(
            (const void*)embB, (const void*)kernB, emb, out);
    } else {
        opn_fused<false><<<dim3(992), 256, 0, stream>>>(
            (const void*)emb, (const void*)kern, emb, out);
    }
}